// Round 17
// baseline (5137.506 us; speedup 1.0000x reference)
//
#include <hip/hip_runtime.h>
#include <hip/hip_bf16.h>
#include <math.h>

#ifndef M_PIf
#define M_PIf 3.14159265358979323846f
#endif

static constexpr int kNFFT = 2048;
static constexpr int kHOP  = 512;
static constexpr int kBINS = 1025;
static constexpr int kT    = 862;
static constexpr int kL    = 441000;
static constexpr int kB    = 4;
static constexpr int kNSIG = 8;
static constexpr int kD    = 2050;
static constexpr int kHD   = 1025;
static constexpr int kDFF  = 8200;
static constexpr int kBS   = kB * kT;   // 3448
static constexpr float kAttnScale = 0.031234752377721214f; // 1/sqrt(1025)
static constexpr long kS2  = (long)kT * kT;    // 743,044
static constexpr int kTP   = 864;
static constexpr long kS2P = (long)kT * kTP;   // 744,768
static constexpr int kHDP  = 1032;   // V row stride
static constexpr int kHDP2 = 1056;   // Q/K row stride (32-mult, glds)
static constexpr int kQKr  = 3488;   // Q/K rows
static constexpr int kWr   = 1152;   // proj W rows (9 x 128)
static constexpr int kWoR  = 2176;   // out-proj W rows (17 x 128)
static constexpr int kNH   = 4104;   // FFN N/K half
static constexpr int kDP2  = 2080;   // K padded to 32-mult (also aout stride)
static constexpr int kNHP  = 4128;   // hid row stride
static constexpr int kMP   = 3456;   // X rows (27 x 128, FFN grid)
static constexpr int kW1R  = 4352;   // FFN W1 rows (17 x 256)
static constexpr int kW2R  = 2304;   // FFN W2 rows (9 x 256)

using bf16 = __hip_bfloat16;
typedef __attribute__((ext_vector_type(4))) float f32x4;
typedef __attribute__((ext_vector_type(8))) short bf16x8;

__device__ __forceinline__ float ldf(const float* p, long i) { return p[i]; }
__device__ __forceinline__ float ldf(const bf16* p, long i) {
  return __bfloat162float(p[i]);
}
__device__ __forceinline__ void sto(float* p, long i, float v) { p[i] = v; }
__device__ __forceinline__ void sto(bf16* p, long i, float v) {
  p[i] = __float2bfloat16(v);
}
__device__ __forceinline__ void load16(const float* src, bf16* dst) {
#pragma unroll
  for (int e = 0; e < 16; ++e) dst[e] = __float2bfloat16(src[e]);
}
__device__ __forceinline__ void load16(const bf16* src, bf16* dst) {
  *(bf16x8*)(dst)     = *(const bf16x8*)(src);
  *(bf16x8*)(dst + 8) = *(const bf16x8*)(src + 8);
}

// Direct global->LDS 16B async copy (wave-uniform LDS base, per-lane src).
__device__ __forceinline__ void glds16(const bf16* g, bf16* l) {
  __builtin_amdgcn_global_load_lds(
      (const __attribute__((address_space(1))) unsigned int*)g,
      (__attribute__((address_space(3))) unsigned int*)l, 16, 0, 0);
}

// Bijective XCD-aware block swizzle (m204).
__device__ __forceinline__ void xcd_swizzle(int& bx, int& by) {
  int nwg = gridDim.x * gridDim.y;
  int orig = by * gridDim.x + bx;
  int qq = nwg >> 3, rr = nwg & 7;
  int xcd = orig & 7, loc = orig >> 3;
  int wg = (xcd < rr ? xcd * (qq + 1) : rr * (qq + 1) + (xcd - rr) * qq) + loc;
  bx = wg % gridDim.x;
  by = wg / gridDim.x;
}

// Register-path staging of one 16-elem bf16 chunk into an LDS row (k_pv).
template <typename T>
__device__ __forceinline__ void stage_row16(const T* S, int grow, int glim,
                                            int lda, int k0sk, int K,
                                            bf16* dst) {
  bf16 tmp[16];
  if (grow < glim && k0sk + 16 <= K) {
    load16(S + (long)grow * lda + k0sk, tmp);
  } else {
#pragma unroll
    for (int e = 0; e < 16; ++e) {
      int gk = k0sk + e;
      tmp[e] = __float2bfloat16(
          (grow < glim && gk < K) ? ldf(S, (long)grow * lda + gk) : 0.f);
    }
  }
  *(bf16x8*)(dst)     = *(bf16x8*)&tmp[0];
  *(bf16x8*)(dst + 8) = *(bf16x8*)&tmp[8];
}

// ---------------------------------------------------------------------------
__global__ void k_twiddle(float2* __restrict__ tw) {
  int m = blockIdx.x * 256 + threadIdx.x;
  if (m < 1024) {
    float s, c;
    sincosf(M_PIf * (float)m / 1024.f, &s, &c);
    tw[m] = make_float2(c, s);
  }
}

__device__ __forceinline__ void fft2048_lds(float*& sr, float*& si,
                                            float* dr, float* di, int tid,
                                            float dir,
                                            const float2* __restrict__ tw) {
  int s = 0;
  for (int Ns = 1; Ns < 2048; Ns <<= 1, ++s) {
#pragma unroll
    for (int q = 0; q < 4; ++q) {
      int j = tid + q * 256;
      int base = j & (Ns - 1);
      int grp = j >> s;
      float2 t = tw[base << (10 - s)];
      float c = t.x, sn = dir * t.y;
      float ar = sr[j],        ai = si[j];
      float br = sr[j + 1024], bi = si[j + 1024];
      float tbr = br * c - bi * sn;
      float tbi = br * sn + bi * c;
      int o = (grp << (s + 1)) + base;
      dr[o]      = ar + tbr;  di[o]      = ai + tbi;
      dr[o + Ns] = ar - tbr;  di[o + Ns] = ai - tbi;
    }
    __syncthreads();
    float* t0 = sr; sr = dr; dr = t0;
    float* t1 = si; si = di; di = t1;
  }
}

__global__ __launch_bounds__(256) void k_stft(const float* __restrict__ mix,
                                              const float* __restrict__ win,
                                              const float2* __restrict__ tw,
                                              float* __restrict__ spec) {
  __shared__ float b0r[2048], b0i[2048], b1r[2048], b1i[2048];
  int t = blockIdx.x, sig = blockIdx.y, tid = threadIdx.x;
  const float* x = mix + (long)sig * kL;
  for (int i = tid; i < 2048; i += 256) {
    int src = t * kHOP + i - 1024;
    if (src < 0) src = -src;
    if (src >= kL) src = 2 * kL - 2 - src;
    b0r[i] = x[src] * win[i];
    b0i[i] = 0.f;
  }
  __syncthreads();
  float* sr = b0r; float* si = b0i;
  fft2048_lds(sr, si, b1r, b1i, tid, -1.f, tw);
  for (int k = tid; k < kBINS; k += 256) {
    long o = ((long)sig * kBINS + k) * kT + t;
    spec[o * 2]     = sr[k];
    spec[o * 2 + 1] = si[k];
  }
}

__global__ __launch_bounds__(256) void k_istft(const float* __restrict__ spec,
                                               const float* __restrict__ win,
                                               const float2* __restrict__ tw,
                                               float* __restrict__ frames) {
  __shared__ float b0r[2048], b0i[2048], b1r[2048], b1i[2048];
  int t = blockIdx.x, sig = blockIdx.y, tid = threadIdx.x;
  for (int k = tid; k < kBINS; k += 256) {
    long o = ((long)sig * kBINS + k) * kT + t;
    b0r[k] = spec[o * 2];
    b0i[k] = spec[o * 2 + 1];
  }
  __syncthreads();
  for (int k = 1025 + tid; k < 2048; k += 256) {
    b0r[k] = b0r[2048 - k];
    b0i[k] = -b0i[2048 - k];
  }
  __syncthreads();
  float* sr = b0r; float* si = b0i;
  fft2048_lds(sr, si, b1r, b1i, tid, +1.f, tw);
  const float scale = 1.f / 2048.f;
  float* fo = frames + ((long)sig * kT + t) * 2048;
  for (int n = tid; n < 2048; n += 256) fo[n] = sr[n] * scale * win[n];
}

__global__ void k_gather(const float* __restrict__ frames,
                         const float* __restrict__ win,
                         float* __restrict__ out0) {
  long idx = (long)blockIdx.x * 256 + threadIdx.x;
  long total = (long)kNSIG * kL;
  if (idx >= total) return;
  int sig = (int)(idx / kL);
  int l = (int)(idx % kL);
  int j = l + 1024;
  int tmax = j >> 9; if (tmax > kT - 1) tmax = kT - 1;
  int v = j - 1536;
  int tmin = v > 0 ? (v >> 9) : 0;
  float acc = 0.f, w2 = 0.f;
  for (int t = tmin; t <= tmax; ++t) {
    int n = j - (t << 9);
    float w = win[n];
    acc += frames[((long)sig * kT + t) * 2048 + n];
    w2 = fmaf(w, w, w2);
  }
  out0[idx] = acc / (w2 > 1e-11f ? w2 : 1.f);
}

// conv1x1 + pos-enc -> bf16 hi/lo split tokens (row stride kDP2).
__global__ void k_conv1_pe(const float* __restrict__ spec,
                           const float* __restrict__ c1wr, const float* __restrict__ c1br,
                           const float* __restrict__ c1wi, const float* __restrict__ c1bi,
                           bf16* __restrict__ xrh, bf16* __restrict__ xrl,
                           bf16* __restrict__ xih, bf16* __restrict__ xil) {
  long idx = (long)blockIdx.x * 256 + threadIdx.x;
  long total = (long)kB * 2 * kBINS * kT;
  if (idx >= total) return;
  int t = (int)(idx % kT);
  long r0 = idx / kT;
  int bin = (int)(r0 % kBINS);
  long r1 = r0 / kBINS;
  int ch = (int)(r1 % 2);
  int b = (int)(r1 / 2);
  float re = spec[idx * 2], im = spec[idx * 2 + 1];
  float wr = c1wr[ch], br = c1br[ch], wi = c1wi[ch], bi = c1bi[ch];
  float nr = (re * wr + br) - (im * wi + bi);
  float ni = (im * wr + br) + (re * wi + bi);
  int d = bin * 2 + ch;
  int k = d >> 1;
  float dv = expf((float)k * (-9.210340371976184f / 1025.0f));
  float arg = (float)t * dv;
  float pe = (d & 1) ? cosf(arg) : sinf(arg);
  long ro = ((long)(b * kT + t)) * kDP2 + d;
  float vr = nr + pe, vi = ni + pe;
  bf16 hr = __float2bfloat16(vr);
  bf16 hi = __float2bfloat16(vi);
  xrh[ro] = hr; xrl[ro] = __float2bfloat16(vr - __bfloat162float(hr));
  xih[ro] = hi; xil[ro] = __float2bfloat16(vi - __bfloat162float(hi));
}

// fp32 -> bf16 convert, zero-fill outside (srows x scols).
__global__ void k_cvt2(const float* __restrict__ src, bf16* __restrict__ dst,
                       long total, int ldd, int srows, int scols, int lds) {
  long idx = (long)blockIdx.x * 256 + threadIdx.x;
  if (idx >= total) return;
  int r = (int)(idx / ldd), c = (int)(idx % ldd);
  float v = (r < srows && c < scols) ? src[(long)r * lds + c] : 0.f;
  dst[idx] = __float2bfloat16(v);
}

// fp32 -> split bf16 (hi + lo), zero-fill outside.
__global__ void k_cvt2s(const float* __restrict__ src, bf16* __restrict__ dh,
                        bf16* __restrict__ dl, long total, int ldd, int srows,
                        int scols, int lds) {
  long idx = (long)blockIdx.x * 256 + threadIdx.x;
  if (idx >= total) return;
  int r = (int)(idx / ldd), c = (int)(idx % ldd);
  float v = (r < srows && c < scols) ? src[(long)r * lds + c] : 0.f;
  bf16 h = __float2bfloat16(v);
  dh[idx] = h;
  dl[idx] = __float2bfloat16(v - __bfloat162float(h));
}

// ===========================================================================
// 8-wave 256(M)x128(N) single-buffered glds GEMM family (round-16 winner).
// Wave layout: 4M x 2N sub-tiles. LDS <= 48KB -> 3 blocks/CU overlap (m114).
// A-side tile over-reads (rows beyond real M) land in the NEXT allocated
// buffer (valid memory); GEMM row-independence => garbage only reaches
// write-guarded output rows. K == lda/ldb (mult of 32, zero-padded cols).
// ===========================================================================

// 2 A's sharing one B: C1 = A1*B^T + bs1*bias, C2 = A2*B^T + bs2*bias.
template <typename TC>
__global__ __launch_bounds__(512) void k_mfma2g(
    const bf16* __restrict__ A1, const bf16* __restrict__ A2,
    const bf16* __restrict__ B, TC* __restrict__ C1, TC* __restrict__ C2,
    const float* __restrict__ bias, float bs1, float bs2,
    int M, int N, int K, int lda, int ldb, int ldc) {
  __shared__ __align__(16) bf16 As1[256][32];
  __shared__ __align__(16) bf16 As2[256][32];
  __shared__ __align__(16) bf16 Bs[128][32];
  int bx = blockIdx.x, by = blockIdx.y;
  xcd_swizzle(bx, by);
  int bm = by * 256, bn = bx * 128;
  int tid = threadIdx.x;
  int lane = tid & 63, w = tid >> 6;
  int wr = (w >> 1) * 64, wc = (w & 1) * 64;
  int fr = lane & 15, fq = lane >> 4;
  f32x4 ac1[4][4] = {}, ac2[4][4] = {};
  int srA = w * 32 + (lane >> 2);   // +c*16 per call
  int srB = w * 16 + (lane >> 2);
  int scol = (lane & 3) * 8;
  const bf16* pA1[2];
  const bf16* pA2[2];
#pragma unroll
  for (int c = 0; c < 2; ++c) {
    long ga = (long)(bm + srA + c * 16) * lda + scol;
    pA1[c] = A1 + ga;
    pA2[c] = A2 + ga;
  }
  const bf16* pB = B + (long)(bn + srB) * ldb + scol;
  for (int k0 = 0; k0 < K; k0 += 32) {
#pragma unroll
    for (int c = 0; c < 2; ++c) {
      int lb = w * 1024 + c * 512;
      glds16(pA1[c] + k0, &As1[0][0] + lb);
      glds16(pA2[c] + k0, &As2[0][0] + lb);
    }
    glds16(pB + k0, &Bs[0][0] + w * 512);
    __syncthreads();
    bf16x8 a1[4], a2[4], b[4];
#pragma unroll
    for (int i = 0; i < 4; ++i) {
      a1[i] = *(const bf16x8*)&As1[wr + i * 16 + fr][fq * 8];
      a2[i] = *(const bf16x8*)&As2[wr + i * 16 + fr][fq * 8];
      b[i]  = *(const bf16x8*)&Bs[wc + i * 16 + fr][fq * 8];
    }
#pragma unroll
    for (int i = 0; i < 4; ++i)
#pragma unroll
      for (int j = 0; j < 4; ++j) {
        ac1[i][j] = __builtin_amdgcn_mfma_f32_16x16x32_bf16(a1[i], b[j], ac1[i][j], 0, 0, 0);
        ac2[i][j] = __builtin_amdgcn_mfma_f32_16x16x32_bf16(a2[i], b[j], ac2[i][j], 0, 0, 0);
      }
    __syncthreads();
  }
#pragma unroll
  for (int i = 0; i < 4; ++i)
#pragma unroll
    for (int j = 0; j < 4; ++j) {
      int gn = bn + wc + j * 16 + fr;
      if (gn >= N) continue;
      float bv = bias ? bias[gn] : 0.f;
#pragma unroll
      for (int r = 0; r < 4; ++r) {
        int gm = bm + wr + i * 16 + fq * 4 + r;
        if (gm >= M) continue;
        long co = (long)gm * ldc + gn;
        sto(C1, co, ac1[i][j][r] + bs1 * bv);
        sto(C2, co, ac2[i][j][r] + bs2 * bv);
      }
    }
}

// Split-precision projection: C = (Ah+Al)@(Bh+Bl)^T + bias (3 products),
// output re-split into hi/lo bf16.
__global__ __launch_bounds__(512) void k_gemm3s8(
    const bf16* __restrict__ Ah, const bf16* __restrict__ Al,
    const bf16* __restrict__ Bh, const bf16* __restrict__ Bl,
    bf16* __restrict__ Ch, bf16* __restrict__ Cl,
    const float* __restrict__ bias,
    int M, int N, int K, int lda, int ldb, int ldc) {
  __shared__ __align__(16) bf16 Sah[256][32];
  __shared__ __align__(16) bf16 Sal[256][32];
  __shared__ __align__(16) bf16 Sbh[128][32];
  __shared__ __align__(16) bf16 Sbl[128][32];
  int bx = blockIdx.x, by = blockIdx.y;
  xcd_swizzle(bx, by);
  int bm = by * 256, bn = bx * 128;
  int tid = threadIdx.x;
  int lane = tid & 63, w = tid >> 6;
  int wr = (w >> 1) * 64, wc = (w & 1) * 64;
  int fr = lane & 15, fq = lane >> 4;
  f32x4 acc[4][4] = {};
  int srA = w * 32 + (lane >> 2);
  int srB = w * 16 + (lane >> 2);
  int scol = (lane & 3) * 8;
  const bf16* pAh[2];
  const bf16* pAl[2];
#pragma unroll
  for (int c = 0; c < 2; ++c) {
    long ga = (long)(bm + srA + c * 16) * lda + scol;
    pAh[c] = Ah + ga;
    pAl[c] = Al + ga;
  }
  long gb = (long)(bn + srB) * ldb + scol;
  const bf16* pBh = Bh + gb;
  const bf16* pBl = Bl + gb;
  for (int k0 = 0; k0 < K; k0 += 32) {
#pragma unroll
    for (int c = 0; c < 2; ++c) {
      int lb = w * 1024 + c * 512;
      glds16(pAh[c] + k0, &Sah[0][0] + lb);
      glds16(pAl[c] + k0, &Sal[0][0] + lb);
    }
    glds16(pBh + k0, &Sbh[0][0] + w * 512);
    glds16(pBl + k0, &Sbl[0][0] + w * 512);
    __syncthreads();
    bf16x8 ah[4], al[4], bh[4], bl[4];
#pragma unroll
    for (int i = 0; i < 4; ++i) {
      ah[i] = *(const bf16x8*)&Sah[wr + i * 16 + fr][fq * 8];
      al[i] = *(const bf16x8*)&Sal[wr + i * 16 + fr][fq * 8];
      bh[i] = *(const bf16x8*)&Sbh[wc + i * 16 + fr][fq * 8];
      bl[i] = *(const bf16x8*)&Sbl[wc + i * 16 + fr][fq * 8];
    }
#pragma unroll
    for (int i = 0; i < 4; ++i)
#pragma unroll
      for (int j = 0; j < 4; ++j) {
        acc[i][j] = __builtin_amdgcn_mfma_f32_16x16x32_bf16(ah[i], bh[j], acc[i][j], 0, 0, 0);
        acc[i][j] = __builtin_amdgcn_mfma_f32_16x16x32_bf16(ah[i], bl[j], acc[i][j], 0, 0, 0);
        acc[i][j] = __builtin_amdgcn_mfma_f32_16x16x32_bf16(al[i], bh[j], acc[i][j], 0, 0, 0);
      }
    __syncthreads();
  }
#pragma unroll
  for (int i = 0; i < 4; ++i)
#pragma unroll
    for (int j = 0; j < 4; ++j) {
      int gn = bn + wc + j * 16 + fr;
      if (gn >= N) continue;
      float bv = bias[gn];
#pragma unroll
      for (int r = 0; r < 4; ++r) {
        int gm = bm + wr + i * 16 + fq * 4 + r;
        if (gm >= M) continue;
        long co = (long)gm * ldc + gn;
        float v = acc[i][j][r] + bv;
        bf16 h = __float2bfloat16(v);
        Ch[co] = h;
        Cl[co] = __float2bfloat16(v - __bfloat162float(h));
      }
    }
}

// Split-precision QK^T. z = bl*4 + combo (combo = qsel*2 + ksel).
__global__ __launch_bounds__(512) void k_qkt38(
    const bf16* __restrict__ Qrh, const bf16* __restrict__ Qrl,
    const bf16* __restrict__ Qih, const bf16* __restrict__ Qil,
    const bf16* __restrict__ Krh, const bf16* __restrict__ Krl,
    const bf16* __restrict__ Kih, const bf16* __restrict__ Kil,
    float* __restrict__ S, int bp) {
  __shared__ __align__(16) bf16 Sqh[256][32];
  __shared__ __align__(16) bf16 Sql[256][32];
  __shared__ __align__(16) bf16 Skh[128][32];
  __shared__ __align__(16) bf16 Skl[128][32];
  int bl = blockIdx.z >> 2, c = blockIdx.z & 3;
  int b = bp * 2 + bl;
  long roff = (long)b * kT * kHDP2;
  const bf16* qh = ((c >> 1) ? Qih : Qrh) + roff;
  const bf16* ql = ((c >> 1) ? Qil : Qrl) + roff;
  const bf16* kh = ((c & 1) ? Kih : Krh) + roff;
  const bf16* kl = ((c & 1) ? Kil : Krl) + roff;
  float* So = S + ((long)bl * 4 + c) * kS2;
  int bx = blockIdx.x, by = blockIdx.y;
  xcd_swizzle(bx, by);
  int bm = by * 256, bn = bx * 128;
  int tid = threadIdx.x;
  int lane = tid & 63, w = tid >> 6;
  int wr = (w >> 1) * 64, wc = (w & 1) * 64;
  int fr = lane & 15, fq = lane >> 4;
  f32x4 acc[4][4] = {};
  int srA = w * 32 + (lane >> 2);
  int srB = w * 16 + (lane >> 2);
  int scol = (lane & 3) * 8;
  const bf16* pQh[2];
  const bf16* pQl[2];
#pragma unroll
  for (int cc = 0; cc < 2; ++cc) {
    long ga = (long)(bm + srA + cc * 16) * kHDP2 + scol;
    pQh[cc] = qh + ga;
    pQl[cc] = ql + ga;
  }
  long gb = (long)(bn + srB) * kHDP2 + scol;
  const bf16* pKh = kh + gb;
  const bf16* pKl = kl + gb;
  for (int k0 = 0; k0 < kHDP2; k0 += 32) {
#pragma unroll
    for (int cc = 0; cc < 2; ++cc) {
      int lb = w * 1024 + cc * 512;
      glds16(pQh[cc] + k0, &Sqh[0][0] + lb);
      glds16(pQl[cc] + k0, &Sql[0][0] + lb);
    }
    glds16(pKh + k0, &Skh[0][0] + w * 512);
    glds16(pKl + k0, &Skl[0][0] + w * 512);
    __syncthreads();
    bf16x8 ah[4], al[4], bh[4], bl[4];
#pragma unroll
    for (int i = 0; i < 4; ++i) {
      ah[i] = *(const bf16x8*)&Sqh[wr + i * 16 + fr][fq * 8];
      al[i] = *(const bf16x8*)&Sql[wr + i * 16 + fr][fq * 8];
      bh[i] = *(const bf16x8*)&Skh[wc + i * 16 + fr][fq * 8];
      bl[i] = *(const bf16x8*)&Skl[wc + i * 16 + fr][fq * 8];
    }
#pragma unroll
    for (int i = 0; i < 4; ++i)
#pragma unroll
      for (int j = 0; j < 4; ++j) {
        acc[i][j] = __builtin_amdgcn_mfma_f32_16x16x32_bf16(ah[i], bh[j], acc[i][j], 0, 0, 0);
        acc[i][j] = __builtin_amdgcn_mfma_f32_16x16x32_bf16(ah[i], bl[j], acc[i][j], 0, 0, 0);
        acc[i][j] = __builtin_amdgcn_mfma_f32_16x16x32_bf16(al[i], bh[j], acc[i][j], 0, 0, 0);
      }
    __syncthreads();
  }
#pragma unroll
  for (int i = 0; i < 4; ++i)
#pragma unroll
    for (int j = 0; j < 4; ++j) {
      int gn = bn + wc + j * 16 + fr;
      if (gn >= kT) continue;
#pragma unroll
      for (int r = 0; r < 4; ++r) {
        int gm = bm + wr + i * 16 + fq * 4 + r;
        if (gm >= kT) continue;
        So[(long)gm * kT + gn] = acc[i][j][r];
      }
    }
}

// Complex-fused FFN GEMM: 128x256 tile, 8 waves, single-buffer (round 16).
template <typename TC>
__global__ __launch_bounds__(512) void k_cgemm(
    const bf16* __restrict__ Ar, const bf16* __restrict__ Ai,
    const bf16* __restrict__ Br, const bf16* __restrict__ Bi,
    TC* __restrict__ Cr, TC* __restrict__ Ci,
    const float* __restrict__ biasR, const float* __restrict__ biasI,
    float bscale, int accum, int relu, int Nreal,
    int M, int N, int K, int lda, int ldb, int ldc) {
  __shared__ __align__(16) bf16 Asr[128][32];
  __shared__ __align__(16) bf16 Asi[128][32];
  __shared__ __align__(16) bf16 Bsr[256][32];
  __shared__ __align__(16) bf16 Bsi[256][32];
  int bx = blockIdx.x, by = blockIdx.y;
  xcd_swizzle(bx, by);
  int bm = by * 128, bn = bx * 256;
  int tid = threadIdx.x;
  int lane = tid & 63, w = tid >> 6;
  int wr = (w >> 2) * 64, wc = (w & 3) * 64;
  int fr = lane & 15, fq = lane >> 4;
  f32x4 acR[4][4] = {}, acI[4][4] = {};
  int srow = w * 16 + (lane >> 2);
  int scol = (lane & 3) * 8;
  const bf16* pAr = Ar + (long)(bm + srow) * lda + scol;
  const bf16* pAi = Ai + (long)(bm + srow) * lda + scol;
  const bf16* pBr[2];
  const bf16* pBi[2];
#pragma unroll
  for (int c = 0; c < 2; ++c) {
    long gb = (long)(bn + c * 128 + srow) * ldb + scol;
    pBr[c] = Br + gb;
    pBi[c] = Bi + gb;
  }
  const short ks = (short)0x8000;
  const bf16x8 sgn = {ks, ks, ks, ks, ks, ks, ks, ks};
  for (int k0 = 0; k0 < K; k0 += 32) {
    glds16(pAr + k0, &Asr[0][0] + w * 512);
    glds16(pAi + k0, &Asi[0][0] + w * 512);
#pragma unroll
    for (int c = 0; c < 2; ++c) {
      int lb = c * 4096 + w * 512;
      glds16(pBr[c] + k0, &Bsr[0][0] + lb);
      glds16(pBi[c] + k0, &Bsi[0][0] + lb);
    }
    __syncthreads();
    bf16x8 ar[4], ai[4], nai[4];
#pragma unroll
    for (int i = 0; i < 4; ++i) {
      ar[i] = *(const bf16x8*)&Asr[wr + i * 16 + fr][fq * 8];
      ai[i] = *(const bf16x8*)&Asi[wr + i * 16 + fr][fq * 8];
      nai[i] = ai[i] ^ sgn;
    }
#pragma unroll
    for (int j = 0; j < 4; ++j) {
      bf16x8 br = *(const bf16x8*)&Bsr[wc + j * 16 + fr][fq * 8];
      bf16x8 bi = *(const bf16x8*)&Bsi[wc + j * 16 + fr][fq * 8];
#pragma unroll
      for (int i = 0; i < 4; ++i) {
        acR[i][j] = __builtin_amdgcn_mfma_f32_16x16x32_bf16(ar[i],  br, acR[i][j], 0, 0, 0);
        acR[i][j] = __builtin_amdgcn_mfma_f32_16x16x32_bf16(nai[i], bi, acR[i][j], 0, 0, 0);
        acI[i][j] = __builtin_amdgcn_mfma_f32_16x16x32_bf16(ai[i],  br, acI[i][j], 0, 0, 0);
        acI[i][j] = __builtin_amdgcn_mfma_f32_16x16x32_bf16(ar[i],  bi, acI[i][j], 0, 0, 0);
      }
    }
    __syncthreads();
  }
#pragma unroll
  for (int i = 0; i < 4; ++i)
#pragma unroll
    for (int j = 0; j < 4; ++j) {
      int gn = bn + wc + j * 16 + fr;
      if (gn >= N) continue;
      float br_ = 0.f, bi_ = 0.f;
      if (gn < Nreal) { br_ = biasR[gn]; bi_ = biasI[gn]; }
#pragma unroll
      for (int r = 0; r < 4; ++r) {
        int gm = bm + wr + i * 16 + fq * 4 + r;
        if (gm >= M) continue;
        long co = (long)gm * ldc + gn;
        float vR = acR[i][j][r] + bscale * (br_ - bi_);
        float vI = acI[i][j][r] + bscale * (br_ + bi_);
        if (accum) { vR += ldf(Cr, co); vI += ldf(Ci, co); }
        if (relu) { vR = fmaxf(vR, 0.f); vI = fmaxf(vI, 0.f); }
        sto(Cr, co, vR);
        sto(Ci, co, vI);
      }
    }
}

// ---------------------------------------------------------------------------
// Fused PV: Cr = P0@Vr + P2@Vi ; Ci = P0@Vi + P1@Vr. B is KxN (register path).
// ---------------------------------------------------------------------------
__global__ __launch_bounds__(256) void k_pv(
    const bf16* __restrict__ P, const bf16* __restrict__ Vr,
    const bf16* __restrict__ Vi, bf16* __restrict__ Cr,
    bf16* __restrict__ Ci, int M, int N, int K, int ldp, int ldv, int ldc) {
  __shared__ __align__(16) bf16 Ps0[128][40];
  __shared__ __align__(16) bf16 Ps1[128][40];
  __shared__ __align__(16) bf16 Ps2[128][40];
  __shared__ __align__(16) bf16 Vsr[128][40];
  __shared__ __align__(16) bf16 Vsi[128][40];
  int tid = threadIdx.x;
  int bm = blockIdx.y * 128, bn = blockIdx.x * 128;
  int lane = tid & 63, w = tid >> 6;
  int wr = (w >> 1) * 64, wc = (w & 1) * 64;
  int fr = lane & 15, fq = lane >> 4;
  f32x4 acR[4][4] = {}, acI[4][4] = {};
  int sr = tid >> 1, sk = (tid & 1) * 16;
  int kk = tid >> 3, nq = (tid & 7) * 16;
  for (int k0 = 0; k0 < K; k0 += 32) {
    stage_row16(P,            bm + sr, M, ldp, k0 + sk, K, &Ps0[sr][sk]);
    stage_row16(P + kS2P,     bm + sr, M, ldp, k0 + sk, K, &Ps1[sr][sk]);
    stage_row16(P + 2 * kS2P, bm + sr, M, ldp, k0 + sk, K, &Ps2[sr][sk]);
    {
      int gk = k0 + kk;
      bf16 t0[16], t1[16];
      if (gk < K && bn + nq + 16 <= N) {
        load16(Vr + (long)gk * ldv + bn + nq, t0);
        load16(Vi + (long)gk * ldv + bn + nq, t1);
      } else {
#pragma unroll
        for (int e = 0; e < 16; ++e) {
          int gn = bn + nq + e;
          bool ok = (gk < K && gn < N);
          t0[e] = __float2bfloat16(ok ? ldf(Vr, (long)gk * ldv + gn) : 0.f);
          t1[e] = __float2bfloat16(ok ? ldf(Vi, (long)gk * ldv + gn) : 0.f);
        }
      }
#pragma unroll
      for (int e = 0; e < 16; ++e) {
        Vsr[nq + e][kk] = t0[e];
        Vsi[nq + e][kk] = t1[e];
      }
    }
    __syncthreads();
    bf16x8 p0[4], p1[4], p2[4], vr[4], vi[4];
#pragma unroll
    for (int i = 0; i < 4; ++i) {
      p0[i] = *(const bf16x8*)&Ps0[wr + i * 16 + fr][fq * 8];
      p1[i] = *(const bf16x8*)&Ps1[wr + i * 16 + fr][fq * 8];
      p2[i] = *(const bf16x8*)&Ps2[wr + i * 16 + fr][fq * 8];
      vr[i] = *(const bf16x8*)&Vsr[wc + i * 16 + fr][fq * 8];
      vi[i] = *(const bf16x8*)&Vsi[wc + i * 16 + fr][fq * 8];
    }
#pragma unroll
    for (int i = 0; i < 4; ++i)
#pragma unroll
      for (int j = 0; j < 4; ++j) {
        acR[i][j] = __builtin_amdgcn_mfma_f32_16x16x32_bf16(p0[i], vr[j], acR[i][j], 0, 0, 0);
        acR[i][j] = __builtin_amdgcn_mfma_f32_16x16x32_bf16(p2[i], vi[j], acR[i][j], 0, 0, 0);
        acI[i][j] = __builtin_amdgcn_mfma_f32_16x16x32_bf16(p0[i], vi[j], acI[i][j], 0, 0, 0);
        acI[i][j] = __builtin_amdgcn_mfma_f32_16x16x32_bf16(p1[i], vr[j], acI[i][j], 0, 0, 0);
      }
    __syncthreads();
  }
#pragma unroll
  for (int i = 0; i < 4; ++i)
#pragma unroll
    for (int j = 0; j < 4; ++j) {
      int gn = bn + wc + j * 16 + fr;
      if (gn >= N) continue;
#pragma unroll
      for (int r = 0; r < 4; ++r) {
        int gm = bm + wr + i * 16 + fq * 4 + r;
        if (gm >= M) continue;
        long co = (long)gm * ldc + gn;
        Cr[co] = __float2bfloat16(acR[i][j][r]);
        Ci[co] = __float2bfloat16(acI[i][j][r]);
      }
    }
}

// Fused softmax over 4 fp32 score mats + fold to 3 bf16 P mats (stride kS2P).
__global__ __launch_bounds__(256) void k_smf(const float* __restrict__ S,
                                             bf16* __restrict__ P) {
  long rbase = (long)blockIdx.x * kT;
  long pbase = (long)blockIdx.x * kTP;
  int tid = threadIdx.x;
  int lane = tid & 63, w = tid >> 6;
  float v[4][4];
  float mx[4] = {-3.4e38f, -3.4e38f, -3.4e38f, -3.4e38f};
#pragma unroll
  for (int c = 0; c < 4; ++c) {
    const float* row = S + c * kS2 + rbase;
#pragma unroll
    for (int q = 0; q < 4; ++q) {
      int i = tid + q * 256;
      v[c][q] = (i < kT) ? row[i] : -3.4e38f;
      mx[c] = fmaxf(mx[c], v[c][q]);
    }
  }
  __shared__ float redm[4][4];
  for (int o = 32; o > 0; o >>= 1)
#pragma unroll
    for (int c = 0; c < 4; ++c) mx[c] = fmaxf(mx[c], __shfl_down(mx[c], o));
  if (lane == 0)
#pragma unroll
    for (int c = 0; c < 4; ++c) redm[w][c] = mx[c];
  __syncthreads();
#pragma unroll
  for (int c = 0; c < 4; ++c)
    mx[c] = fmaxf(fmaxf(redm[0][c], redm[1][c]), fmaxf(redm[2][c], redm[3][c]));
  __syncthreads();
  float sm[4] = {0.f, 0.f, 0.f, 0.f};
#pragma unroll
  for (int c = 0; c < 4; ++c)
#pragma unroll
    for (int q = 0; q < 4; ++q) {
      int i = tid + q * 256;
      if (i < kT) {
        v[c][q] = expf(kAttnScale * (v[c][q] - mx[c]));
        sm[c] += v[c][q];
      }
    }
  __shared__ float reds[4][4];
  for (int o = 32; o > 0; o >>= 1)
#pragma unroll
    for (int c = 0; c < 4; ++c) sm[c] += __shfl_down(sm[c], o);
  if (lane == 0)
#pragma unroll
    for (int c = 0; c < 4; ++c) reds[w][c] = sm[c];
  __syncthreads();
  float inv[4];
#pragma unroll
  for (int c = 0; c < 4; ++c)
    inv[c] = 1.f / (reds[0][c] + reds[1][c] + reds[2][c] + reds[3][c]);
  bf16* p0 = P + pbase;
  bf16* p1 = P + kS2P + pbase;
  bf16* p2 = P + 2 * kS2P + pbase;
#pragma unroll
  for (int q = 0; q < 4; ++q) {
    int i = tid + q * 256;
    if (i >= kT) continue;
    float a0 = v[0][q] * inv[0], a1 = v[1][q] * inv[1];
    float a2 = v[2][q] * inv[2], a3 = v[3][q] * inv[3];
    p0[i] = __float2bfloat16(a0 - a3);
    p1[i] = __float2bfloat16(a1 + a2);
    p2[i] = __float2bfloat16(a1 - a2);
  }
}

__global__ __launch_bounds__(256) void k_ln(float* __restrict__ X,
                                            const float* __restrict__ g,
                                            const float* __restrict__ b, int d) {
  long row = blockIdx.x;
  float* x = X + row * d;
  int tid = threadIdx.x;
  float s = 0.f, s2 = 0.f;
  for (int i = tid; i < d; i += 256) {
    float v = x[i];
    s += v;
    s2 = fmaf(v, v, s2);
  }
  __shared__ float rs[4], rs2[4];
  for (int o = 32; o > 0; o >>= 1) {
    s += __shfl_down(s, o);
    s2 += __shfl_down(s2, o);
  }
  int lane = tid & 63, w = tid >> 6;
  if (lane == 0) { rs[w] = s; rs2[w] = s2; }
  __syncthreads();
  float st = rs[0] + rs[1] + rs[2] + rs[3];
  float s2t = rs2[0] + rs2[1] + rs2[2] + rs2[3];
  float m = st / d;
  float var = s2t / d - m * m;
  float inv = rsqrtf(var + 1e-5f);
  for (int i = tid; i < d; i += 256) x[i] = (x[i] - m) * inv * g[i] + b[i];
}

__global__ void k_mask(const float* __restrict__ gr_, const float* __restrict__ gi_,
                       const float* __restrict__ c2wr, const float* __restrict__ c2br,
                       const float* __restrict__ c2wi, const float* __restrict__ c2bi,
                       float* __restrict__ spec) {
  long idx = (long)blockIdx.x * 256 + threadIdx.x;
  long total = (long)kB * 2 * kBINS * kT;
  if (idx >= total) return;
  int t = (int)(idx % kT);
  long r0 = idx / kT;
  int bin = (int)(r0 % kBINS);
  long r1 = r0 / kBINS;
  int ch = (int)(r1 % 2);
  int b = (int)(r1 / 2);
  long ro = ((long)(b * kT + t)) * kD + (bin * 2 + ch);
  float gr = gr_[ro], gi = gi_[ro];
  float wr = c2wr[ch], br = c2br[ch], wi = c2wi[ch], bi = c2bi[ch];
  float mr = (gr * wr + br) - (gi * wi + bi);
  float mi = (gi * wr + br) + (gr * wi + bi);
  float re = spec[idx * 2], im = spec[idx * 2 + 1];
  spec[idx * 2]     = re / (1.f + expf(-mr));
  spec[idx * 2 + 1] = im / (1.f + expf(-mi));
}

extern "C" void kernel_launch(void* const* d_in, const int* in_sizes, int n_in,
                              void* d_out, int out_size, void* d_ws, size_t ws_size,
                              hipStream_t stream) {
  const float* mix        = (const float*)d_in[0];
  const float* window     = (const float*)d_in[1];
  const float* c1wr       = (const float*)d_in[2];
  const float* c1br       = (const float*)d_in[3];
  const float* c1wi       = (const float*)d_in[4];
  const float* c1bi       = (const float*)d_in[5];
  const float* c2wr       = (const float*)d_in[6];
  const float* c2br       = (const float*)d_in[7];
  const float* c2wi       = (const float*)d_in[8];
  const float* c2bi       = (const float*)d_in[9];
  const float* attn_in_w  = (const float*)d_in[10];
  const float* attn_in_b  = (const float*)d_in[11];
  const float* attn_out_w = (const float*)d_in[12];
  const float* attn_out_b = (const float*)d_in[13];
  const float* l1wr       = (const float*)d_in[14];
  const float* l1br       = (const float*)d_in[15];
  const float* l1wi       = (const float*)d_in[16];
  const float* l1bi       = (const float*)d_in[17];
  const float* l2wr       = (const float*)d_in[18];
  const float* l2br       = (const float*)d_in[19];
  const float* l2wi       = (const float*)d_in[20];
  const float* l2bi       = (const float*)d_in[21];
  const float* n1_gr      = (const float*)d_in[22];
  const float* n1_br      = (const float*)d_in[23];
  const float* n1_gi      = (const float*)d_in[24];
  const float* n1_bi      = (const float*)d_in[25];
  const float* n2_gr      = (const float*)d_in[26];
  const float* n2_br      = (const float*)d_in[27];
  const float* n2_gi      = (const float*)d_in[28];
  const float* n2_bi      = (const float*)d_in[29];

  // ---- workspace layout (bytes), all constexpr. kNeed = 187,800,192.
  constexpr long eX    = (long)kMP * kDP2;     // 7,188,480
  constexpr long eQK2  = (long)kQKr * kHDP2;   // 3,683,328
  constexpr long eAout = (long)kBS * kDP2;     // 7,171,840 (stride 2080)
  constexpr long eV    = (long)kBS * kHDP;     // 3,558,336
  constexpr long eWp   = (long)kWr * kDP2;     // 2,396,160
  constexpr long eHidp = (long)kMP * kNHP;     // 14,266,368
  constexpr long eW1p  = (long)kW1R * kDP2;    // 9,052,160
  constexpr long eW2p  = (long)kW2R * kNHP;    // 9,510,912

  constexpr size_t oX    = 0;
  constexpr size_t oQK   = oX + 4 * eX * 2;            //  57,507,840
  constexpr size_t oAout = oQK + 8 * eQK2 * 2;         // 116,441,088
  constexpr size_t oV    = oAout + 2 * eAout * 2;      // 145,128,448
  constexpr size_t oW    = oV + 2 * eV * 2;            // 159,361,792
  constexpr size_t oP    = oW + 5 * eWp * 2;           // 183,323,392
  constexpr size_t oTW   = oP + 3 * kS2P * 2;          // 187,792,000
  constexpr size_t kNeed = oTW + 8192;                 // 187,800,192
  static_assert(kNeed <= 188922816, "ws ceiling");
  constexpr size_t oSS = oW;                           // scores overlay W
  static_assert(oSS + 8 * kS2 * 4 <= oP, "sS overflow");
  static_assert(2 * (long)kBS * kD * 4 <= (long)oQK, "xr/xi overlay");
  static_assert((long)kWoR * kDP2 * 2 <= (long)(oW - oV), "Wob overlay");
  // FFN overlays (attention dead):
  constexpr size_t oAb  = oQK;
  constexpr size_t oWF  = oAb + 2 * eX * 2;            //  86,261,760
  constexpr size_t oHid = oWF + 2 * eW2p * 2;          // 124,305,408
  static_assert(2 * eW1p * 2 <= 2 * eW2p * 2, "W slot sized by W2");
  static_assert(oHid + 2 * eHidp * 2 <= oTW, "hid overflow");
  static_assert((long)kNSIG * kT * 2048 * 4 <= (long)(oTW - oAb), "frames");

  char* wsb = (char*)d_ws;
  if (ws_size < kNeed) return;  // fail signature: out0 all-zero (2.578125)

  bf16*  Xrh = (bf16*)(wsb + oX);
  bf16*  Xrl = Xrh + eX;
  bf16*  Xih = Xrl + eX;
  bf16*  Xil = Xih + eX;
  bf16*  Qrh = (bf16*)(wsb + oQK);
  bf16*  Qrl = Qrh + eQK2;
  bf16*  Qih = Qrl + eQK2;
  bf16*  Qil = Qih + eQK2;
  bf16*  Krh = Qil + eQK2;
  bf16*  Krl = Krh + eQK2;
  bf16*  Kih = Krl + eQK2;
  bf16*  Kil = Kih + eQK2;
  bf16*  aoutR = (bf16*)(wsb + oAout);
  bf16*  aoutI = aoutR + eAout;
  bf16*  Vr = (bf16*)(wsb + oV);
  bf16*  Vi = Vr + eV;
  bf16*  Wqh = (bf16*)(wsb + oW);
  bf16*  Wql = Wqh + eWp;
  bf16*  Wkh = Wql + eWp;
  bf16*  Wkl = Wkh + eWp;
  bf16*  Wvh = Wkl + eWp;
  float* sS = (float*)(wsb + oSS);
  bf16*  Pbuf = (bf16*)(wsb + oP);
  bf16*  Wob = (bf16*)(wsb + oV);          // out-proj W (V dead)
  float* xr = (float*)(wsb + oX);          // post-attn fp32 (X dead)
  float* xi = xr + (long)kBS * kD;
  // FFN pointers:
  bf16*  AbR = (bf16*)(wsb + oAb);
  bf16*  AbI = AbR + eX;
  bf16*  w1rH = (bf16*)(wsb + oWF);
  bf16*  w1iH = w1rH + eW1p;
  bf16*  w2rH = (bf16*)(wsb + oWF);
  bf16*  w2iH = w2rH + eW2p;
  bf16*  hidR = (bf16*)(wsb + oHid);
  bf16*  hidI = hidR + eHidp;
  float* frames = (float*)(wsb + oAb);
  float2* tw = (float2*)(wsb + oTW);

  float* out0 = (float*)d_out;
  float* spec = out0 + (long)kNSIG * kL;

  auto cvt2 = [&](const float* src, bf16* dst, int dstRows, int ldd,
                  int srows, int scols, int lds) {
    long total = (long)dstRows * ldd;
    k_cvt2<<<(int)((total + 255) / 256), 256, 0, stream>>>(src, dst, total,
                                                           ldd, srows, scols,
                                                           lds);
  };
  auto cvt2s = [&](const float* src, bf16* dh, bf16* dl, int dstRows, int ldd,
                   int srows, int scols, int lds) {
    long total = (long)dstRows * ldd;
    k_cvt2s<<<(int)((total + 255) / 256), 256, 0, stream>>>(
        src, dh, dl, total, ldd, srows, scols, lds);
  };

  // 0) zero workspace (pads must be zero for glds paths), twiddle table
  hipMemsetAsync(d_ws, 0, kNeed, stream);
  k_twiddle<<<4, 256, 0, stream>>>(tw);

  // 1) STFT -> spec (out1)
  k_stft<<<dim3(kT, kNSIG), 256, 0, stream>>>(mix, window, tw, spec);

  // 2) conv1 + pos-enc -> split-bf16 tokens (stride kDP2)
  long nct = (long)kB * 2 * kBINS * kT;
  k_conv1_pe<<<(nct + 255) / 256, 256, 0, stream>>>(spec, c1wr, c1br, c1wi,
                                                    c1bi, Xrh, Xrl, Xih, Xil);

  // 3) attention, per head (all GEMMs on the 8-wave 256x128 structure)
  for (int h = 0; h < 2; ++h) {
    const float* Wq = attn_in_w + (long)(h * kHD) * kD;
    const float* Wk = attn_in_w + (long)(kD + h * kHD) * kD;
    const float* Wv = attn_in_w + (long)(2 * kD + h * kHD) * kD;
    const float* bq = attn_in_b + h * kHD;
    const float* bk = attn_in_b + kD + h * kHD;
    const float* bv = attn_in_b + 2 * kD + h * kHD;
    cvt2s(Wq, Wqh, Wql, kWr, kDP2, kHD, kD, kD);
    cvt2s(Wk, Wkh, Wkl, kWr, kDP2, kHD, kD, kD);
    cvt2(Wv, Wvh, kWr, kDP2, kHD, kD, kD);
    // V projection
    k_mfma2g<bf16><<<dim3(9, 14), 512, 0, stream>>>(
        Xrh, Xih, Wvh, Vr, Vi, bv, 1.f, 1.f, kBS, kHD, kDP2, kDP2, kDP2, kHDP);
    // Q, K projections (split precision)
    k_gemm3s8<<<dim3(9, 14), 512, 0, stream>>>(
        Xrh, Xrl, Wqh, Wql, Qrh, Qrl, bq, kBS, kHD, kDP2, kDP2, kDP2, kHDP2);
    k_gemm3s8<<<dim3(9, 14), 512, 0, stream>>>(
        Xih, Xil, Wqh, Wql, Qih, Qil, bq, kBS, kHD, kDP2, kDP2, kDP2, kHDP2);
    k_gemm3s8<<<dim3(9, 14), 512, 0, stream>>>(
        Xrh, Xrl, Wkh, Wkl, Krh, Krl, bk, kBS, kHD, kDP2, kDP2, kDP2, kHDP2);
    k_gemm3s8<<<dim3(9, 14), 512, 0, stream>>>(
        Xih, Xil, Wkh, Wkl, Kih, Kil, bk, kBS, kHD, kDP2, kDP2, kDP2, kHDP2);
    for (int bp = 0; bp < 2; ++bp) {
      k_qkt38<<<dim3(7, 4, 8), 512, 0, stream>>>(Qrh, Qrl, Qih, Qil,
                                                 Krh, Krl, Kih, Kil, sS, bp);
      for (int bl = 0; bl < 2; ++bl) {
        int b = bp * 2 + bl;
        k_smf<<<kT, 256, 0, stream>>>(sS + (long)bl * 4 * kS2, Pbuf);
        k_pv<<<dim3(9, 7), 256, 0, stream>>>(
            Pbuf, Vr + (long)b * kT * kHDP, Vi + (long)b * kT * kHDP,
            aoutR + (long)b * kT * kDP2 + h * kHD,
            aoutI + (long)b * kT * kDP2 + h * kHD,
            kT, kHD, kT, kTP, kHDP, kDP2);
      }
    }
  }

  // 4) output projection -> fp32 xr, xi (X arena; X dead).
  //    aout cols 2050..2079 stay zero (memset; k_pv never writes them).
  cvt2(attn_out_w, Wob, kWoR, kDP2, kD, kD, kD);
  k_mfma2g<float><<<dim3(17, 14), 512, 0, stream>>>(
      aoutR, aoutI, Wob, xr, xi, attn_out_b, 0.f, 2.f,
      kBS, kD, kDP2, kDP2, kDP2, kD);

  // 5) LN1
  k_ln<<<kBS, 256, 0, stream>>>(xr, n1_gr, n1_br, kD);
  k_ln<<<kBS, 256, 0, stream>>>(xi, n1_gi, n1_bi, kD);

  // 6) FFN (complex-fused, 128x256 tile / 8 waves / single-buffer LDS)
  cvt2(xr, AbR, kMP, kDP2, kBS, kD, kD);
  cvt2(xi, AbI, kMP, kDP2, kBS, kD, kD);
  for (int nh = 0; nh < 2; ++nh) {
    int srows = (nh ? kDFF - kNH : kNH);   // 4096 : 4104
    cvt2(l1wr + (long)nh * kNH * kD, w1rH, kW1R, kDP2, srows, kD, kD);
    cvt2(l1wi + (long)nh * kNH * kD, w1iH, kW1R, kDP2, srows, kD, kD);
    k_cgemm<bf16><<<dim3(17, 27), 512, 0, stream>>>(
        AbR, AbI, w1rH, w1iH, hidR, hidI,
        l1br + nh * kNH, l1bi + nh * kNH, 1.f, 0, 1, srows,
        kBS, kNHP, kDP2, kDP2, kDP2, kNHP);
    cvt2(l2wr + nh * kNH, w2rH, kW2R, kNHP, kD, srows, kDFF);
    cvt2(l2wi + nh * kNH, w2iH, kW2R, kNHP, kD, srows, kDFF);
    k_cgemm<float><<<dim3(9, 27), 512, 0, stream>>>(
        hidR, hidI, w2rH, w2iH, xr, xi,
        l2br, l2bi, (nh == 0 ? 1.f : 0.f), nh, 0, kD,
        kBS, kD, kNHP, kNHP, kNHP, kD);
  }

  // 7) LN2
  k_ln<<<kBS, 256, 0, stream>>>(xr, n2_gr, n2_br, kD);
  k_ln<<<kBS, 256, 0, stream>>>(xi, n2_gi, n2_bi, kD);

  // 8) mask + gate spec in place
  k_mask<<<(nct + 255) / 256, 256, 0, stream>>>(xr, xi, c2wr, c2br, c2wi,
                                                c2bi, spec);

  // 9) iSTFT + overlap-add
  k_istft<<<dim3(kT, kNSIG), 256, 0, stream>>>(spec, window, tw, frames);
  k_gather<<<(int)(((long)kNSIG * kL + 255) / 256), 256, 0, stream>>>(
      frames, window, out0);
}